// Round 1
// baseline (645.066 us; speedup 1.0000x reference)
//
#include <hip/hip_runtime.h>

#define NREL 53
#define FEAT 690
#define NBAGS 512
#define SMAX 128
#define K2 106      // 53 (m) + 53 (r_embed) projection columns
#define FC 46       // f-chunk for proj GEMM (690 = 15*46)
#define NCH 15

// ---------------- kernel 1: m[r][g] = sum_f r_embed[r][f] * att_W[r][f][g] ----------------
// grid: (3 g-chunks, 5 f-chunks, 53 r). Memory-bound on att_W (101 MB).
__global__ __launch_bounds__(256) void k_m(const float* __restrict__ r_embed,
                                           const float* __restrict__ att_W,
                                           float* __restrict__ m_ws) {
    const int gc = blockIdx.x, fc = blockIdx.y, r = blockIdx.z;
    const int g = gc * 256 + threadIdx.x;
    const int f0 = fc * 138;                 // 690 = 5 * 138
    __shared__ float re[138];
    for (int i = threadIdx.x; i < 138; i += 256) re[i] = r_embed[r * FEAT + f0 + i];
    __syncthreads();
    if (g >= FEAT) return;
    const float* aw = att_W + (size_t)r * FEAT * FEAT + (size_t)f0 * FEAT + g;
    float acc = 0.f;
    #pragma unroll 2
    for (int j = 0; j < 138; ++j) acc += re[j] * aw[(size_t)j * FEAT];
    atomicAdd(&m_ws[r * FEAT + g], acc);
}

// ---------------- kernel 2: proj[b][s][k] = feat[b,s,:] . M2[k,:]  (s < L only) ----------
// One block per bag. 128 rows x 128 cols (106 live) register-tiled fp32 GEMM.
__global__ __launch_bounds__(256) void k_proj(const float* __restrict__ features,
                                              const int* __restrict__ lengths,
                                              const float* __restrict__ r_embed,
                                              const float* __restrict__ m_ws,
                                              float* __restrict__ proj) {
    const int b = blockIdx.x;
    const int L = lengths[b];
    __shared__ float Alds[FC][129];   // transposed: [f][s]
    __shared__ float Blds[FC][129];   // transposed: [f][k], cols >=106 zero-padded
    const int tid = threadIdx.x;
    const int r0 = (tid >> 4) * 8;    // 8 rows / thread
    const int c0 = (tid & 15) * 8;    // 8 cols / thread
    float acc[8][8] = {};
    const float* fb = features + (size_t)b * SMAX * FEAT;

    for (int ch = 0; ch < NCH; ++ch) {
        const int f0 = ch * FC;
        // stage A (valid rows only), transposed
        for (int idx = tid; idx < L * FC; idx += 256) {
            const int s = idx / FC, j = idx - s * FC;
            Alds[j][s] = fb[(size_t)s * FEAT + f0 + j];
        }
        // stage B rows 0..127 (k<53: m, 53..105: r_embed, rest zero), transposed
        for (int idx = tid; idx < 128 * FC; idx += 256) {
            const int k = idx / FC, j = idx - k * FC;
            float v = 0.f;
            if (k < NREL)      v = m_ws[k * FEAT + f0 + j];
            else if (k < K2)   v = r_embed[(k - NREL) * FEAT + f0 + j];
            Blds[j][k] = v;
        }
        __syncthreads();
        if (r0 < L) {
            for (int j = 0; j < FC; ++j) {
                float a[8], bb[8];
                #pragma unroll
                for (int i = 0; i < 8; ++i) a[i] = Alds[j][r0 + i];
                #pragma unroll
                for (int n = 0; n < 8; ++n) bb[n] = Blds[j][c0 + n];
                #pragma unroll
                for (int i = 0; i < 8; ++i)
                    #pragma unroll
                    for (int n = 0; n < 8; ++n) acc[i][n] += a[i] * bb[n];
            }
        }
        __syncthreads();
    }
    float* pb = proj + (size_t)b * SMAX * K2;
    for (int i = 0; i < 8; ++i) {
        const int s = r0 + i;
        if (s >= L) break;
        #pragma unroll
        for (int n = 0; n < 8; ++n) {
            const int k = c0 + n;
            if (k < K2) pb[(size_t)s * K2 + k] = acc[i][n];
        }
    }
}

// ---------------- kernel 3: per-bag softmax + weighted contraction + log_softmax + max ----
__global__ __launch_bounds__(256) void k_finish(const float* __restrict__ proj,
                                                const int* __restrict__ lengths,
                                                const float* __restrict__ r_bias,
                                                float* __restrict__ out) {
    const int b = blockIdx.x;
    const int L = lengths[b];
    __shared__ float p[SMAX][K2 + 1];   // 54.8 KB
    __shared__ float w[NREL][SMAX];     // 27.1 KB
    __shared__ float sc[NREL][NREL + 1];
    __shared__ float lse[NREL];
    const int tid = threadIdx.x;
    const int wv = tid >> 6, lane = tid & 63;

    const float* pb = proj + (size_t)b * SMAX * K2;
    for (int idx = tid; idx < L * K2; idx += 256) {
        const int s = idx / K2, k = idx - s * K2;
        p[s][k] = pb[idx];
    }
    __syncthreads();

    // masked softmax over s for each of the 53 relation rows; fold *0.5
    for (int r = wv; r < NREL; r += 4) {
        float v0 = (lane < L)      ? p[lane][r]      : -1e30f;
        float v1 = (lane + 64 < L) ? p[lane + 64][r] : -1e30f;
        float mx = fmaxf(v0, v1);
        for (int o = 32; o; o >>= 1) mx = fmaxf(mx, __shfl_xor(mx, o));
        float e0 = (lane < L)      ? __expf(v0 - mx) : 0.f;
        float e1 = (lane + 64 < L) ? __expf(v1 - mx) : 0.f;
        float sm = e0 + e1;
        for (int o = 32; o; o >>= 1) sm += __shfl_xor(sm, o);
        const float inv = 0.5f / sm;
        if (lane < L)      w[r][lane]      = e0 * inv;
        if (lane + 64 < L) w[r][lane + 64] = e1 * inv;
    }
    __syncthreads();

    // scores[r][k] = sum_s w[r][s] * p[s][53+k] + bias[k]
    for (int o = tid; o < NREL * NREL; o += 256) {
        const int r = o / NREL, k = o - r * NREL;
        float acc = 0.f;
        for (int s = 0; s < L; ++s) acc += w[r][s] * p[s][NREL + k];
        sc[r][k] = acc + r_bias[k];
    }
    __syncthreads();

    // per-row logsumexp over k
    for (int r = wv; r < NREL; r += 4) {
        const float v = (lane < NREL) ? sc[r][lane] : -1e30f;
        float mx = v;
        for (int o = 32; o; o >>= 1) mx = fmaxf(mx, __shfl_xor(mx, o));
        float e = (lane < NREL) ? __expf(v - mx) : 0.f;
        for (int o = 32; o; o >>= 1) e += __shfl_xor(e, o);
        if (lane == 0) lse[r] = mx + __logf(e);
    }
    __syncthreads();

    if (tid < NREL) {
        float best = -1e30f;
        for (int r = 0; r < NREL; ++r) best = fmaxf(best, sc[r][tid] - lse[r]);
        out[b * NREL + tid] = best;
    }
}

extern "C" void kernel_launch(void* const* d_in, const int* in_sizes, int n_in,
                              void* d_out, int out_size, void* d_ws, size_t ws_size,
                              hipStream_t stream) {
    const float* features = (const float*)d_in[0];   // [512,128,690]
    const int*   lengths  = (const int*)d_in[1];     // [512]
    const float* r_embed  = (const float*)d_in[2];   // [53,690]
    const float* r_bias   = (const float*)d_in[3];   // [53]
    const float* att_W    = (const float*)d_in[4];   // [53,690,690]
    float* out  = (float*)d_out;                     // [512,53]

    float* m_ws = (float*)d_ws;                                  // 53*690 floats
    float* proj = (float*)((char*)d_ws + (1 << 18));             // 512*128*106 floats (~27.8 MB)

    hipMemsetAsync(m_ws, 0, NREL * FEAT * sizeof(float), stream);

    dim3 g1(3, 5, NREL);
    k_m<<<g1, 256, 0, stream>>>(r_embed, att_W, m_ws);
    k_proj<<<NBAGS, 256, 0, stream>>>(features, lengths, r_embed, m_ws, proj);
    k_finish<<<NBAGS, 256, 0, stream>>>(proj, lengths, r_bias, out);
}

// Round 2
// 557.058 us; speedup vs baseline: 1.1580x; 1.1580x over previous
//
#include <hip/hip_runtime.h>

#define NREL 53
#define FEAT 690
#define NBAGS 512
#define SMAX 128
#define K2 106      // 53 (m) + 53 (r_embed) projection columns
#define FC 46       // f-chunk (690 = 15*46)
#define NCH 15
#define ASTR 132    // Alds row stride in words (16B-aligned, CF for broadcast reads)
#define BSTR 128    // Blds row stride in words

// ---------------- kernel 1: m[r][g] = sum_f r_embed[r][f] * att_W[r][f][g] ----------------
__global__ __launch_bounds__(256) void k_m(const float* __restrict__ r_embed,
                                           const float* __restrict__ att_W,
                                           float* __restrict__ m_ws) {
    const int gc = blockIdx.x, fc = blockIdx.y, r = blockIdx.z;
    const int g = gc * 512 + threadIdx.x * 2;
    const int f0 = fc * 138;                 // 690 = 5 * 138
    __shared__ float re[138];
    for (int i = threadIdx.x; i < 138; i += 256) re[i] = r_embed[r * FEAT + f0 + i];
    __syncthreads();
    if (g >= FEAT) return;
    const float* aw = att_W + (size_t)r * FEAT * FEAT + (size_t)f0 * FEAT + g;
    float ax = 0.f, ay = 0.f;
    #pragma unroll 4
    for (int j = 0; j < 138; ++j) {
        const float2 v = *(const float2*)&aw[(size_t)j * FEAT];
        ax += re[j] * v.x;
        ay += re[j] * v.y;
    }
    atomicAdd(&m_ws[r * FEAT + g], ax);
    atomicAdd(&m_ws[r * FEAT + g + 1], ay);
}

// ---------------- kernel 2: projT[b][k][s] = feat[b,s,:] . M2[k,:]  (s < L only) ----------
// One block per bag, 128(s) x 128(k, 106 live) tile, 8x8 per thread, b128 LDS reads.
__global__ __launch_bounds__(256) void k_proj(const float* __restrict__ features,
                                              const int* __restrict__ lengths,
                                              const float* __restrict__ r_embed,
                                              const float* __restrict__ m_ws,
                                              float* __restrict__ projT) {
    const int b = blockIdx.x;
    const int L = lengths[b];
    __shared__ __align__(16) float Alds[FC * ASTR];   // [f][s] transposed
    __shared__ __align__(16) float Blds[FC * BSTR];   // [f][col'(k)] swizzled
    const int tid = threadIdx.x;
    const int r0 = (tid >> 4) * 8;    // 8 s-rows / thread
    const int u  = tid & 15;          // col group: k = 8u..8u+7
    float acc[8][8] = {};
    const float* fb = features + (size_t)b * SMAX * FEAT;
    const int La = L * 23;

    for (int ch = 0; ch < NCH; ++ch) {
        const int f0 = ch * FC;
        // stage A (valid rows only), float2, transposed -> Alds[j][s]
        for (int idx = tid; idx < La; idx += 256) {
            const int s = idx / 23, j2 = (idx - s * 23) * 2;
            const float2 v = *(const float2*)&fb[(size_t)s * FEAT + f0 + j2];
            Alds[j2 * ASTR + s]       = v.x;
            Alds[(j2 + 1) * ASTR + s] = v.y;
        }
        // stage B rows k=0..127 (k<53: m, 53..105: r_embed, rest zero), swizzled cols
        for (int idx = tid; idx < 128 * 23; idx += 256) {
            const int k = idx / 23, j2 = (idx - k * 23) * 2;
            float2 v = make_float2(0.f, 0.f);
            if (k < NREL)      v = *(const float2*)&m_ws[k * FEAT + f0 + j2];
            else if (k < K2)   v = *(const float2*)&r_embed[(k - NREL) * FEAT + f0 + j2];
            const int cp = ((k >> 3) << 2) + ((k & 4) << 4) + (k & 3);   // bijective swizzle
            Blds[j2 * BSTR + cp]       = v.x;
            Blds[(j2 + 1) * BSTR + cp] = v.y;
        }
        __syncthreads();
        if (r0 < L) {
            #pragma unroll 2
            for (int j = 0; j < FC; ++j) {
                const float4 a0 = *(const float4*)&Alds[j * ASTR + r0];
                const float4 a1 = *(const float4*)&Alds[j * ASTR + r0 + 4];
                const float4 b0 = *(const float4*)&Blds[j * BSTR + 4 * u];        // k=8u..8u+3
                const float4 b1 = *(const float4*)&Blds[j * BSTR + 4 * u + 64];   // k=8u+4..8u+7
                const float a[8]  = {a0.x, a0.y, a0.z, a0.w, a1.x, a1.y, a1.z, a1.w};
                const float bb[8] = {b0.x, b0.y, b0.z, b0.w, b1.x, b1.y, b1.z, b1.w};
                #pragma unroll
                for (int i = 0; i < 8; ++i)
                    #pragma unroll
                    for (int n = 0; n < 8; ++n) acc[i][n] += a[i] * bb[n];
            }
        }
        __syncthreads();
    }
    if (r0 < L) {
        float* pT = projT + (size_t)b * K2 * SMAX;
        #pragma unroll
        for (int n = 0; n < 8; ++n) {
            const int k = 8 * u + n;
            if (k < K2) {
                *(float4*)&pT[k * SMAX + r0]     = make_float4(acc[0][n], acc[1][n], acc[2][n], acc[3][n]);
                *(float4*)&pT[k * SMAX + r0 + 4] = make_float4(acc[4][n], acc[5][n], acc[6][n], acc[7][n]);
            }
        }
    }
}

// ---------------- kernel 3: per-bag softmax + contraction + log_softmax + max ------------
__global__ __launch_bounds__(256) void k_finish(const float* __restrict__ projT,
                                                const int* __restrict__ lengths,
                                                const float* __restrict__ r_bias,
                                                float* __restrict__ out) {
    const int b = blockIdx.x;
    const int L = lengths[b];
    __shared__ float wS[SMAX * 61];     // w[s][r], odd stride: conflict-free
    __shared__ float pRs[SMAX * 61];    // pR[s][k]
    __shared__ float sc[NREL * 56];
    __shared__ float lse[NREL];
    const int tid = threadIdx.x;
    const int wv = tid >> 6, lane = tid & 63;
    const float* pb = projT + (size_t)b * K2 * SMAX;

    // stage pRs[s][k] = projT[b][53+k][s]  (coalesced row reads)
    for (int idx = tid; idx < NREL * SMAX; idx += 256) {
        const int k = idx >> 7, s = idx & 127;
        pRs[s * 61 + k] = pb[(size_t)(NREL + k) * SMAX + s];
    }
    // masked softmax over s for each relation row (read logit rows from global); fold *0.5
    for (int r = wv; r < NREL; r += 4) {
        const float* row = pb + (size_t)r * SMAX;
        float v0 = (lane < L)      ? row[lane]      : -1e30f;
        float v1 = (lane + 64 < L) ? row[lane + 64] : -1e30f;
        float mx = fmaxf(v0, v1);
        for (int o = 32; o; o >>= 1) mx = fmaxf(mx, __shfl_xor(mx, o));
        float e0 = (lane < L)      ? __expf(v0 - mx) : 0.f;
        float e1 = (lane + 64 < L) ? __expf(v1 - mx) : 0.f;
        float sm = e0 + e1;
        for (int o = 32; o; o >>= 1) sm += __shfl_xor(sm, o);
        const float inv = 0.5f / sm;
        if (lane < L)      wS[lane * 61 + r]       = e0 * inv;
        if (lane + 64 < L) wS[(lane + 64) * 61 + r] = e1 * inv;
    }
    __syncthreads();

    // sc[r][k] = sum_s wS[s][r] * pRs[s][k] + bias[k]; 4x4 register tiles
    {
        const int ty = tid >> 4, tx = tid & 15;
        if (ty < 14 && tx < 14) {
            const int rr = ty * 4, kk = tx * 4;
            float a4[4][4] = {};
            for (int s = 0; s < L; ++s) {
                float aa[4], bb[4];
                #pragma unroll
                for (int i = 0; i < 4; ++i) aa[i] = wS[s * 61 + rr + i];
                #pragma unroll
                for (int n = 0; n < 4; ++n) bb[n] = pRs[s * 61 + kk + n];
                #pragma unroll
                for (int i = 0; i < 4; ++i)
                    #pragma unroll
                    for (int n = 0; n < 4; ++n) a4[i][n] += aa[i] * bb[n];
            }
            #pragma unroll
            for (int i = 0; i < 4; ++i) {
                const int r = rr + i;
                if (r < NREL) {
                    #pragma unroll
                    for (int n = 0; n < 4; ++n) {
                        const int k = kk + n;
                        if (k < NREL) sc[r * 56 + k] = a4[i][n] + r_bias[k];
                    }
                }
            }
        }
    }
    __syncthreads();

    // per-row logsumexp over k
    for (int r = wv; r < NREL; r += 4) {
        const float v = (lane < NREL) ? sc[r * 56 + lane] : -1e30f;
        float mx = v;
        for (int o = 32; o; o >>= 1) mx = fmaxf(mx, __shfl_xor(mx, o));
        float e = (lane < NREL) ? __expf(v - mx) : 0.f;
        for (int o = 32; o; o >>= 1) e += __shfl_xor(e, o);
        if (lane == 0) lse[r] = mx + __logf(e);
    }
    __syncthreads();

    if (tid < NREL) {
        float best = -1e30f;
        for (int r = 0; r < NREL; ++r) best = fmaxf(best, sc[r * 56 + tid] - lse[r]);
        out[b * NREL + tid] = best;
    }
}

extern "C" void kernel_launch(void* const* d_in, const int* in_sizes, int n_in,
                              void* d_out, int out_size, void* d_ws, size_t ws_size,
                              hipStream_t stream) {
    const float* features = (const float*)d_in[0];   // [512,128,690]
    const int*   lengths  = (const int*)d_in[1];     // [512]
    const float* r_embed  = (const float*)d_in[2];   // [53,690]
    const float* r_bias   = (const float*)d_in[3];   // [53]
    const float* att_W    = (const float*)d_in[4];   // [53,690,690]
    float* out  = (float*)d_out;                     // [512,53]

    float* m_ws  = (float*)d_ws;                               // 53*690 floats
    float* projT = (float*)((char*)d_ws + (1 << 18));          // 512*106*128 floats

    hipMemsetAsync(m_ws, 0, NREL * FEAT * sizeof(float), stream);

    dim3 g1(2, 5, NREL);
    k_m<<<g1, 256, 0, stream>>>(r_embed, att_W, m_ws);
    k_proj<<<NBAGS, 256, 0, stream>>>(features, lengths, r_embed, m_ws, projT);
    k_finish<<<NBAGS, 256, 0, stream>>>(projT, lengths, r_bias, out);
}

// Round 3
// 362.954 us; speedup vs baseline: 1.7773x; 1.5348x over previous
//
#include <hip/hip_runtime.h>

#define NREL 53
#define FEAT 690
#define NBAGS 512
#define SMAX 128
#define K2 106        // 53 (m) + 53 (r_embed) projection columns
#define KPAD 704      // FEAT padded to 22*32
#define NT 22         // K-steps of 32
#define LDSTR 40      // LDS row stride in shorts (80 B: <=2-way banks for b128)

typedef short bf16x8 __attribute__((ext_vector_type(8)));
typedef short short4v __attribute__((ext_vector_type(4)));
typedef short short8v __attribute__((ext_vector_type(8)));
typedef float f32x4 __attribute__((ext_vector_type(4)));

__device__ __forceinline__ short f2bf(float x) {   // RNE, finite inputs
    union { float f; unsigned u; } c; c.f = x;
    unsigned r = c.u + 0x7fffu + ((c.u >> 16) & 1u);
    return (short)(r >> 16);
}

// ---------------- kernel 1: m[r][g] = sum_f r_embed[r][f] * att_W[r][f][g] ----------------
// f-chunks of 30, fully unrolled -> 30 independent float2 loads in flight (latency fix).
#define FCH 30
__global__ __launch_bounds__(256) void k_m(const float* __restrict__ r_embed,
                                           const float* __restrict__ att_W,
                                           float* __restrict__ m_ws) {
    const int gc = blockIdx.x, fc = blockIdx.y, r = blockIdx.z;
    const int g = gc * 512 + threadIdx.x * 2;
    const int f0 = fc * FCH;
    __shared__ float re[FCH];
    if (threadIdx.x < FCH) re[threadIdx.x] = r_embed[r * FEAT + f0 + threadIdx.x];
    __syncthreads();
    if (g >= FEAT) return;
    const float* aw = att_W + (size_t)r * FEAT * FEAT + (size_t)f0 * FEAT + g;
    float ax = 0.f, ay = 0.f;
    #pragma unroll
    for (int j = 0; j < FCH; ++j) {
        const float2 t = *(const float2*)&aw[(size_t)j * FEAT];
        ax += re[j] * t.x;
        ay += re[j] * t.y;
    }
    atomicAdd(&m_ws[r * FEAT + g], ax);
    atomicAdd(&m_ws[r * FEAT + g + 1], ay);
}

// ---------------- kernel 1b: Bws[n][f] bf16, n<53: m, 53..105: r_embed, else/pad: 0 -------
__global__ __launch_bounds__(256) void k_prep(const float* __restrict__ m_ws,
                                              const float* __restrict__ r_embed,
                                              short* __restrict__ Bws) {
    const int n = blockIdx.x;          // 0..127
    for (int f = threadIdx.x; f < KPAD; f += 256) {
        float v = 0.f;
        if (f < FEAT) {
            if (n < NREL)    v = m_ws[n * FEAT + f];
            else if (n < K2) v = r_embed[(n - NREL) * FEAT + f];
        }
        Bws[n * KPAD + f] = f2bf(v);
    }
}

// ---------------- kernel 2: projT[b][k][s] = feat[b,s,:] . M2[k,:]  (bf16 MFMA) ----------
// One block per bag: 128(s) x 128(k) tile, 4 waves x (64x64), K-loop of 32, dbuf LDS.
__global__ __launch_bounds__(256) void k_proj(const float* __restrict__ features,
                                              const int* __restrict__ lengths,
                                              const short* __restrict__ Bws,
                                              float* __restrict__ projT) {
    const int b = blockIdx.x;
    const int L = lengths[b];
    __shared__ short Ash[2][128 * LDSTR];
    __shared__ short Bsh[2][128 * LDSTR];
    const int tid = threadIdx.x;
    const int wave = tid >> 6, lane = tid & 63;
    const int wr = (wave >> 1) * 64, wc = (wave & 1) * 64;
    const int r16 = lane & 15, g = lane >> 4;
    const float* fb = features + (size_t)b * SMAX * FEAT;

    f32x4 acc[4][4];
    #pragma unroll
    for (int m = 0; m < 4; ++m)
        #pragma unroll
        for (int n = 0; n < 4; ++n) acc[m][n] = (f32x4)0.f;

    const int srow = tid >> 3;          // A staging row within slab
    const int fo   = (tid & 7) * 4;     // A staging col quad
    const int bn   = tid >> 2;          // B staging row within half
    const int bc   = (tid & 3) * 8;     // B staging col (shorts)

    // ---- prologue: stage kt = 0 into buf 0
    {
        #pragma unroll
        for (int it = 0; it < 4; ++it) {
            if (it * 32 < L) {
                const int s = it * 32 + srow;
                const float* p = fb + (size_t)s * FEAT + fo;
                const float2 v0 = *(const float2*)p;
                const float2 v1 = *(const float2*)(p + 2);
                short4v w = {f2bf(v0.x), f2bf(v0.y), f2bf(v1.x), f2bf(v1.y)};
                *(short4v*)&Ash[0][s * LDSTR + fo] = w;
            }
        }
        #pragma unroll
        for (int jt = 0; jt < 2; ++jt) {
            const int n = jt * 64 + bn;
            *(short8v*)&Bsh[0][n * LDSTR + bc] =
                *(const short8v*)&Bws[n * KPAD + bc];
        }
    }
    __syncthreads();

    int cur = 0;
    for (int kt = 0; kt < NT; ++kt) {
        const bool have_next = (kt + 1 < NT);
        float2 av[4][2];
        short8v bv[2];
        if (have_next) {
            const int k0n = (kt + 1) * 32;
            const bool lastn = (kt + 1 == NT - 1);
            #pragma unroll
            for (int it = 0; it < 4; ++it) {
                if (it * 32 < L) {
                    const int s = it * 32 + srow;
                    const int f0 = k0n + fo;
                    const float* p = fb + (size_t)s * FEAT + f0;
                    if (!lastn) {
                        av[it][0] = *(const float2*)p;
                        av[it][1] = *(const float2*)(p + 2);
                    } else {
                        av[it][0] = (f0 + 1 < FEAT) ? *(const float2*)p       : make_float2(0.f, 0.f);
                        av[it][1] = (f0 + 3 < FEAT) ? *(const float2*)(p + 2) : make_float2(0.f, 0.f);
                    }
                }
            }
            #pragma unroll
            for (int jt = 0; jt < 2; ++jt) {
                const int n = jt * 64 + bn;
                bv[jt] = *(const short8v*)&Bws[n * KPAD + k0n + bc];
            }
        }

        // ---- compute on buf[cur]
        if (wr < L) {
            const short* Ab = &Ash[cur][0];
            const short* Bb = &Bsh[cur][0];
            bf16x8 af[4], bfv[4];
            #pragma unroll
            for (int m = 0; m < 4; ++m)
                af[m] = *(const bf16x8*)&Ab[(wr + m * 16 + r16) * LDSTR + g * 8];
            #pragma unroll
            for (int n = 0; n < 4; ++n)
                bfv[n] = *(const bf16x8*)&Bb[(wc + n * 16 + r16) * LDSTR + g * 8];
            #pragma unroll
            for (int m = 0; m < 4; ++m)
                #pragma unroll
                for (int n = 0; n < 4; ++n)
                    acc[m][n] = __builtin_amdgcn_mfma_f32_16x16x32_bf16(af[m], bfv[n], acc[m][n], 0, 0, 0);
        }

        // ---- write next tile into buf[cur^1]
        if (have_next) {
            #pragma unroll
            for (int it = 0; it < 4; ++it) {
                if (it * 32 < L) {
                    const int s = it * 32 + srow;
                    short4v w = {f2bf(av[it][0].x), f2bf(av[it][0].y),
                                 f2bf(av[it][1].x), f2bf(av[it][1].y)};
                    *(short4v*)&Ash[cur ^ 1][s * LDSTR + fo] = w;
                }
            }
            #pragma unroll
            for (int jt = 0; jt < 2; ++jt) {
                const int n = jt * 64 + bn;
                *(short8v*)&Bsh[cur ^ 1][n * LDSTR + bc] = bv[jt];
            }
        }
        __syncthreads();
        cur ^= 1;
    }

    // ---- epilogue: C/D layout col=lane&15, row=(lane>>4)*4+reg
    if (wr < L) {
        float* pT = projT + (size_t)b * K2 * SMAX;
        #pragma unroll
        for (int m = 0; m < 4; ++m) {
            const int s0 = wr + m * 16 + g * 4;
            if (s0 < L) {
                #pragma unroll
                for (int n = 0; n < 4; ++n) {
                    const int k = wc + n * 16 + r16;
                    if (k < K2) *(f32x4*)&pT[k * SMAX + s0] = acc[m][n];
                }
            }
        }
    }
}

// ---------------- kernel 3: per-bag softmax + contraction + log_softmax + max ------------
__global__ __launch_bounds__(256) void k_finish(const float* __restrict__ projT,
                                                const int* __restrict__ lengths,
                                                const float* __restrict__ r_bias,
                                                float* __restrict__ out) {
    const int b = blockIdx.x;
    const int L = lengths[b];
    __shared__ float wS[SMAX * 61];     // w[s][r], odd stride: conflict-free
    __shared__ float pRs[SMAX * 61];    // pR[s][k]
    __shared__ float sc[NREL * 56];
    __shared__ float lse[NREL];
    const int tid = threadIdx.x;
    const int wv = tid >> 6, lane = tid & 63;
    const float* pb = projT + (size_t)b * K2 * SMAX;

    for (int idx = tid; idx < NREL * SMAX; idx += 256) {
        const int k = idx >> 7, s = idx & 127;
        pRs[s * 61 + k] = pb[(size_t)(NREL + k) * SMAX + s];
    }
    for (int r = wv; r < NREL; r += 4) {
        const float* row = pb + (size_t)r * SMAX;
        float v0 = (lane < L)      ? row[lane]      : -1e30f;
        float v1 = (lane + 64 < L) ? row[lane + 64] : -1e30f;
        float mx = fmaxf(v0, v1);
        for (int o = 32; o; o >>= 1) mx = fmaxf(mx, __shfl_xor(mx, o));
        float e0 = (lane < L)      ? __expf(v0 - mx) : 0.f;
        float e1 = (lane + 64 < L) ? __expf(v1 - mx) : 0.f;
        float sm = e0 + e1;
        for (int o = 32; o; o >>= 1) sm += __shfl_xor(sm, o);
        const float inv = 0.5f / sm;
        if (lane < L)      wS[lane * 61 + r]        = e0 * inv;
        if (lane + 64 < L) wS[(lane + 64) * 61 + r] = e1 * inv;
    }
    __syncthreads();

    {
        const int ty = tid >> 4, tx = tid & 15;
        if (ty < 14 && tx < 14) {
            const int rr = ty * 4, kk = tx * 4;
            float a4[4][4] = {};
            for (int s = 0; s < L; ++s) {
                float aa[4], bb[4];
                #pragma unroll
                for (int i = 0; i < 4; ++i) aa[i] = wS[s * 61 + rr + i];
                #pragma unroll
                for (int n = 0; n < 4; ++n) bb[n] = pRs[s * 61 + kk + n];
                #pragma unroll
                for (int i = 0; i < 4; ++i)
                    #pragma unroll
                    for (int n = 0; n < 4; ++n) a4[i][n] += aa[i] * bb[n];
            }
            #pragma unroll
            for (int i = 0; i < 4; ++i) {
                const int r = rr + i;
                if (r < NREL) {
                    #pragma unroll
                    for (int n = 0; n < 4; ++n) {
                        const int k = kk + n;
                        if (k < NREL) sc[r * 56 + k] = a4[i][n] + r_bias[k];
                    }
                }
            }
        }
    }
    __syncthreads();

    for (int r = wv; r < NREL; r += 4) {
        const float v = (lane < NREL) ? sc[r * 56 + lane] : -1e30f;
        float mx = v;
        for (int o = 32; o; o >>= 1) mx = fmaxf(mx, __shfl_xor(mx, o));
        float e = (lane < NREL) ? __expf(v - mx) : 0.f;
        for (int o = 32; o; o >>= 1) e += __shfl_xor(e, o);
        if (lane == 0) lse[r] = mx + __logf(e);
    }
    __syncthreads();

    if (tid < NREL) {
        float best = -1e30f;
        for (int r = 0; r < NREL; ++r) best = fmaxf(best, sc[r * 56 + tid] - lse[r]);
        out[b * NREL + tid] = best;
    }
}

extern "C" void kernel_launch(void* const* d_in, const int* in_sizes, int n_in,
                              void* d_out, int out_size, void* d_ws, size_t ws_size,
                              hipStream_t stream) {
    const float* features = (const float*)d_in[0];   // [512,128,690]
    const int*   lengths  = (const int*)d_in[1];     // [512]
    const float* r_embed  = (const float*)d_in[2];   // [53,690]
    const float* r_bias   = (const float*)d_in[3];   // [53]
    const float* att_W    = (const float*)d_in[4];   // [53,690,690]
    float* out = (float*)d_out;                      // [512,53]

    float* m_ws  = (float*)d_ws;                                 // 146 KB
    short* Bws   = (short*)((char*)d_ws + (1 << 18));            // 176 KB bf16 B-matrix
    float* projT = (float*)((char*)d_ws + (1 << 19));            // 27.8 MB

    hipMemsetAsync(m_ws, 0, NREL * FEAT * sizeof(float), stream);

    dim3 g1(2, 23, NREL);
    k_m<<<g1, 256, 0, stream>>>(r_embed, att_W, m_ws);
    k_prep<<<128, 256, 0, stream>>>(m_ws, r_embed, Bws);
    k_proj<<<NBAGS, 256, 0, stream>>>(features, lengths, Bws, projT);
    k_finish<<<NBAGS, 256, 0, stream>>>(projT, lengths, r_bias, out);
}